// Round 1
// baseline (418.289 us; speedup 1.0000x reference)
//
#include <hip/hip_runtime.h>

#define HH 192
#define WW 192
#define LL (HH * WW)   // 36864
#define CC 512
#define KK 64
#define EPSF 1e-12f

// ---------------------------------------------------------------- k0: wT[c][k] = conv_w[k][c]
__global__ __launch_bounds__(256) void k0_transpose(const float* __restrict__ w,
                                                    float* __restrict__ wT) {
    int idx = blockIdx.x * 256 + threadIdx.x;   // 32768 = KK*CC
    int k = idx >> 9;        // / 512
    int c = idx & 511;
    wT[c * KK + k] = w[idx];
}

// ---------------------------------------------------------------- k1: per-pixel norm + logits + softmax + top2
// soft[k][l], invn[l], keep[l] (bitmask of top-2 clusters)
__global__ __launch_bounds__(128) void k1_logits(const float* __restrict__ x,
                                                 const float* __restrict__ wT,
                                                 float* __restrict__ soft,
                                                 float* __restrict__ invn,
                                                 unsigned long long* __restrict__ keep) {
    int l = blockIdx.x * 128 + threadIdx.x;
    float acc[KK];
#pragma unroll
    for (int k = 0; k < KK; ++k) acc[k] = 0.f;
    float ss = 0.f;
    for (int c = 0; c < CC; ++c) {
        float xv = x[c * LL + l];
        ss = fmaf(xv, xv, ss);
        const float* wr = wT + c * KK;   // lane-uniform -> scalar loads
#pragma unroll
        for (int k = 0; k < KK; ++k) acc[k] = fmaf(wr[k], xv, acc[k]);
    }
    float inv = 1.0f / fmaxf(sqrtf(ss), EPSF);
    invn[l] = inv;
    float mx = -3.0e38f;
#pragma unroll
    for (int k = 0; k < KK; ++k) { acc[k] *= inv; mx = fmaxf(mx, acc[k]); }
    float sum = 0.f;
#pragma unroll
    for (int k = 0; k < KK; ++k) { float e = expf(acc[k] - mx); acc[k] = e; sum += e; }
    float rs = 1.0f / sum;
    // top-2 (on exp values: monotonic in logits; strict > matches top_k tie-break)
    float m1 = -1.f, m2 = -1.f; int i1 = 0, i2 = 0;
#pragma unroll
    for (int k = 0; k < KK; ++k) {
        float v = acc[k];
        if (v > m1)      { m2 = m1; i2 = i1; m1 = v; i1 = k; }
        else if (v > m2) { m2 = v; i2 = k; }
    }
#pragma unroll
    for (int k = 0; k < KK; ++k) soft[k * LL + l] = acc[k] * rs;
    keep[l] = (1ull << i1) | (1ull << i2);
}

// ---------------------------------------------------------------- k2: weight = soft * neighbor_top2_count * border^4  (in place)
__global__ __launch_bounds__(128) void k2_weight(float* __restrict__ soft,
                                                 const unsigned long long* __restrict__ keep) {
    int l = blockIdx.x * 128 + threadIdx.x;
    int i = l / WW, j = l % WW;
    int m = min(min(i, HH - 1 - i), min(j, WW - 1 - j));
    float bm = (float)m; bm *= bm; bm *= bm;   // m^4
    unsigned long long nb[9];
#pragma unroll
    for (int di = -1; di <= 1; ++di)
#pragma unroll
        for (int dj = -1; dj <= 1; ++dj) {
            int ii = i + di, jj = j + dj;
            nb[(di + 1) * 3 + (dj + 1)] =
                (ii >= 0 && ii < HH && jj >= 0 && jj < WW) ? keep[ii * WW + jj] : 0ull;
        }
#pragma unroll
    for (int k = 0; k < KK; ++k) {
        int cnt = 0;
#pragma unroll
        for (int t = 0; t < 9; ++t) cnt += (int)((nb[t] >> k) & 1ull);
        soft[k * LL + l] *= (float)cnt * bm;
    }
}

// ---------------------------------------------------------------- k3: accg[k][c] += sum_l weight[k][l] * x[c][l] * invn[l]
#define LT 32
#define CT 128
#define NCHUNK 64
#define CHUNK (LL / NCHUNK)   // 576

__global__ __launch_bounds__(256) void k3_gemm(const float* __restrict__ weight,
                                               const float* __restrict__ x,
                                               const float* __restrict__ invn,
                                               float* __restrict__ accg) {
    __shared__ float wt[LT][KK + 1];    // pad 65: kills store/load bank conflicts
    __shared__ float xt[LT][CT + 1];    // pad 129
    int chunk = blockIdx.x & (NCHUNK - 1);
    int ctile = blockIdx.x >> 6;
    int l0 = chunk * CHUNK;
    int c0 = ctile * CT;
    int tid = threadIdx.x;
    int tx = tid & 31, ty = tid >> 5;   // thread computes k = ty+8r (r<8), c = c0+tx+32s (s<4)
    float acc[8][4];
#pragma unroll
    for (int r = 0; r < 8; ++r)
#pragma unroll
        for (int s = 0; s < 4; ++s) acc[r][s] = 0.f;

    for (int lb = 0; lb < CHUNK; lb += LT) {
        int ll = tid & 31;
        int rb = tid >> 5;              // 0..7
        int gl = l0 + lb + ll;
        float iv = invn[gl];
#pragma unroll
        for (int p = 0; p < 8; ++p) {
            int k = rb + 8 * p;
            wt[ll][k] = weight[k * LL + gl];
        }
#pragma unroll
        for (int p = 0; p < 16; ++p) {
            int c = rb + 8 * p;
            xt[ll][c] = x[(c0 + c) * LL + gl] * iv;
        }
        __syncthreads();
#pragma unroll 4
        for (int lt = 0; lt < LT; ++lt) {
            float wv[8], xv[4];
#pragma unroll
            for (int r = 0; r < 8; ++r) wv[r] = wt[lt][ty + 8 * r];
#pragma unroll
            for (int s = 0; s < 4; ++s) xv[s] = xt[lt][tx + 32 * s];
#pragma unroll
            for (int r = 0; r < 8; ++r)
#pragma unroll
                for (int s = 0; s < 4; ++s) acc[r][s] = fmaf(wv[r], xv[s], acc[r][s]);
        }
        __syncthreads();
    }
#pragma unroll
    for (int r = 0; r < 8; ++r)
#pragma unroll
        for (int s = 0; s < 4; ++s)
            atomicAdd(&accg[(ty + 8 * r) * CC + c0 + tx + 32 * s], acc[r][s]);
}

// ---------------------------------------------------------------- k4a: per-row S_k, centroid subtract, row L2-norm
__global__ __launch_bounds__(256) void k4a_rownorm(const float* __restrict__ weight,
                                                   const float* __restrict__ accg,
                                                   const float* __restrict__ cent,
                                                   float* __restrict__ out,
                                                   float* __restrict__ gsum) {
    __shared__ float red[256];
    int k = blockIdx.x;
    int tid = threadIdx.x;
    float s = 0.f;
    for (int l = tid; l < LL; l += 256) s += weight[k * LL + l];
    red[tid] = s; __syncthreads();
    for (int off = 128; off > 0; off >>= 1) {
        if (tid < off) red[tid] += red[tid + off];
        __syncthreads();
    }
    float S = red[0];
    __syncthreads();
    float v0 = accg[k * CC + tid]       - S * cent[k * CC + tid];
    float v1 = accg[k * CC + tid + 256] - S * cent[k * CC + tid + 256];
    red[tid] = v0 * v0 + v1 * v1; __syncthreads();
    for (int off = 128; off > 0; off >>= 1) {
        if (tid < off) red[tid] += red[tid + off];
        __syncthreads();
    }
    float tot = red[0];
    float rn = 1.0f / fmaxf(sqrtf(tot), EPSF);
    out[k * CC + tid]       = v0 * rn;
    out[k * CC + tid + 256] = v1 * rn;
    if (tid == 0) atomicAdd(gsum, tot * rn * rn);
}

// ---------------------------------------------------------------- k4b: global L2 scale
__global__ __launch_bounds__(256) void k4b_gnorm(float* __restrict__ out,
                                                 const float* __restrict__ gsum) {
    float g = gsum[0];
    float rg = 1.0f / fmaxf(sqrtf(g), EPSF);
    int idx = blockIdx.x * 256 + threadIdx.x;
    out[idx] *= rg;
}

// ----------------------------------------------------------------
extern "C" void kernel_launch(void* const* d_in, const int* in_sizes, int n_in,
                              void* d_out, int out_size, void* d_ws, size_t ws_size,
                              hipStream_t stream) {
    const float* x      = (const float*)d_in[0];   // (512,192,192)
    const float* conv_w = (const float*)d_in[1];   // (64,512)
    const float* cent   = (const float*)d_in[2];   // (64,512)
    float* out = (float*)d_out;                    // 32768 fp32

    float* ws   = (float*)d_ws;
    float* wT   = ws;                              // 32768 floats
    float* soft = ws + 32768;                      // KK*LL floats (becomes weight in-place)
    float* invn = soft + (size_t)KK * LL;          // LL floats
    unsigned long long* keep = (unsigned long long*)(invn + LL);  // LL u64 (8B aligned)
    float* accg = (float*)(keep + LL);             // KK*CC floats
    float* gsum = accg + (size_t)KK * CC;          // 1 float

    hipMemsetAsync(accg, 0, ((size_t)KK * CC + 1) * sizeof(float), stream);

    k0_transpose<<<(KK * CC) / 256, 256, 0, stream>>>(conv_w, wT);
    k1_logits<<<LL / 128, 128, 0, stream>>>(x, wT, soft, invn, keep);
    k2_weight<<<LL / 128, 128, 0, stream>>>(soft, keep);
    k3_gemm<<<NCHUNK * (CC / CT), 256, 0, stream>>>(soft, x, invn, accg);
    k4a_rownorm<<<KK, 256, 0, stream>>>(soft, accg, cent, out, gsum);
    k4b_gnorm<<<(KK * CC) / 256, 256, 0, stream>>>(out, gsum);
}

// Round 2
// 267.346 us; speedup vs baseline: 1.5646x; 1.5646x over previous
//
#include <hip/hip_runtime.h>

#define HH 192
#define WW 192
#define LL (HH * WW)   // 36864
#define CC 512
#define KK 64
#define EPSF 1e-12f
typedef unsigned long long ull;

// ---------------------------------------------------------------- k0: wT[c][k] = conv_w[k][c]
__global__ __launch_bounds__(256) void k0_transpose(const float* __restrict__ w,
                                                    float* __restrict__ wT) {
    int idx = blockIdx.x * 256 + threadIdx.x;   // 32768 = KK*CC
    int k = idx >> 9;
    int c = idx & 511;
    wT[c * KK + k] = w[idx];
}

// ---------------------------------------------------------------- k1: lane=k wave-GEMM + softmax + top2
// soft layout: [l][k]. 16 pixels per wave; x pixel values ride in SGPRs.
#define LPW 16
__global__ __launch_bounds__(256) void k1_logits(const float* __restrict__ x,
                                                 const float* __restrict__ wT,
                                                 float* __restrict__ soft,
                                                 float* __restrict__ invn,
                                                 ull* __restrict__ keep) {
    __shared__ float wls[64 * KK];   // 16 KB: one 64-c chunk of wT, [cc][k]
    int tid = threadIdx.x;
    int lane = tid & 63;
    int wid = tid >> 6;              // 0..3
    int l0 = blockIdx.x * (4 * LPW) + wid * LPW;
    l0 = __builtin_amdgcn_readfirstlane(l0);   // force wave-uniform -> s_load path
    int lp = lane & 15;

    float acc[LPW];
#pragma unroll
    for (int p = 0; p < LPW; ++p) acc[p] = 0.f;
    float ss = 0.f;

    for (int cb = 0; cb < CC; cb += 64) {
        __syncthreads();
#pragma unroll
        for (int t = 0; t < 16; ++t) {
            int idx = t * 256 + tid;             // 4096 floats
            wls[idx] = wT[cb * KK + idx];
        }
        __syncthreads();
#pragma unroll 4
        for (int cc = 0; cc < 64; ++cc) {
            const float* xp = x + (cb + cc) * LL + l0;   // wave-uniform base
            float wv = wls[cc * KK + lane];
            float xq = xp[lp];                   // divergent (lanes 0..15 pattern) -> vector load
            ss = fmaf(xq, xq, ss);
#pragma unroll
            for (int p = 0; p < LPW; ++p) acc[p] = fmaf(xp[p], wv, acc[p]);
        }
    }

    float invv = 1.0f / fmaxf(sqrtf(ss), EPSF);
    if (lane < LPW) invn[l0 + lane] = invv;

#pragma unroll
    for (int p = 0; p < LPW; ++p) {
        float ip = __shfl(invv, p, 64);
        float lg = acc[p] * ip;
        // wave max (m1)
        float m1 = lg;
#pragma unroll
        for (int off = 32; off; off >>= 1) m1 = fmaxf(m1, __shfl_xor(m1, off, 64));
        ull b1 = __ballot(lg == m1);
        int i1 = __ffsll((long long)b1) - 1;
        // second max excluding lane i1 (dup values at other lanes still count)
        float lg2 = (lane == i1) ? -3.0e38f : lg;
        float m2 = lg2;
#pragma unroll
        for (int off = 32; off; off >>= 1) m2 = fmaxf(m2, __shfl_xor(m2, off, 64));
        ull b2 = __ballot((lg == m2) && (lane != i1));
        int i2 = __ffsll((long long)b2) - 1;
        float e = __expf(lg - m1);
        float s = e;
#pragma unroll
        for (int off = 32; off; off >>= 1) s += __shfl_xor(s, off, 64);
        soft[(l0 + p) * KK + lane] = e / s;      // coalesced 256B store
        if (lane == 0) keep[l0 + p] = (1ull << i1) | (1ull << i2);
    }
}

// ---------------------------------------------------------------- k2: weight[l][k] = soft * nbr_top2_count * border^4 (in place)
__global__ __launch_bounds__(256) void k2_weight(float* __restrict__ soft,
                                                 const ull* __restrict__ keep) {
    int l = blockIdx.x * 256 + threadIdx.x;
    int i = l / WW, j = l % WW;
    int m = min(min(i, HH - 1 - i), min(j, WW - 1 - j));
    float bm = (float)m; bm *= bm; bm *= bm;   // m^4
    ull nb[9];
#pragma unroll
    for (int di = -1; di <= 1; ++di)
#pragma unroll
        for (int dj = -1; dj <= 1; ++dj) {
            int ii = i + di, jj = j + dj;
            nb[(di + 1) * 3 + (dj + 1)] =
                (ii >= 0 && ii < HH && jj >= 0 && jj < WW) ? keep[ii * WW + jj] : 0ull;
        }
    float4* sp = (float4*)&soft[(size_t)l * KK];
#pragma unroll
    for (int q = 0; q < 16; ++q) {
        float4 v = sp[q];
        int b = q * 4;
        int n0 = 0, n1 = 0, n2 = 0, n3 = 0;
#pragma unroll
        for (int t = 0; t < 9; ++t) {
            ull nv = nb[t] >> b;
            n0 += (int)(nv & 1); n1 += (int)((nv >> 1) & 1);
            n2 += (int)((nv >> 2) & 1); n3 += (int)((nv >> 3) & 1);
        }
        v.x *= (float)n0 * bm; v.y *= (float)n1 * bm;
        v.z *= (float)n2 * bm; v.w *= (float)n3 * bm;
        sp[q] = v;
    }
}

// ---------------------------------------------------------------- k2b: S[k] = sum_l weight[l][k]  (coalesced)
__global__ __launch_bounds__(256) void k2b_ssum(const float* __restrict__ w,
                                                float* __restrict__ S) {
    __shared__ float red[256];
    int tid = threadIdx.x;
    int k = tid & 63, r = tid >> 6;
    int l0 = blockIdx.x * 256;
    float s = 0.f;
    for (int t = 0; t < 64; ++t)
        s += w[(size_t)(l0 + r + 4 * t) * KK + k];
    red[tid] = s; __syncthreads();
    if (r == 0)
        atomicAdd(&S[k], red[k] + red[64 + k] + red[128 + k] + red[192 + k]);
}

// ---------------------------------------------------------------- k3: accg[k][c] += sum_l weight[l][k] * x[c][l] * invn[l]
#define LT 32
#define CT 128
#define NCHUNK 128
#define CHUNK (LL / NCHUNK)   // 288

__global__ __launch_bounds__(256) void k3_gemm(const float* __restrict__ weight,
                                               const float* __restrict__ x,
                                               const float* __restrict__ invn,
                                               float* __restrict__ accg) {
    __shared__ float wt[LT][KK + 1];
    __shared__ float xt[LT][CT + 1];
    int chunk = blockIdx.x & (NCHUNK - 1);
    int ctile = blockIdx.x >> 7;
    int l0 = chunk * CHUNK;
    int c0 = ctile * CT;
    int tid = threadIdx.x;
    int tx = tid & 31, ty = tid >> 5;
    float acc[8][4];
#pragma unroll
    for (int r = 0; r < 8; ++r)
#pragma unroll
        for (int s = 0; s < 4; ++s) acc[r][s] = 0.f;

    for (int lb = 0; lb < CHUNK; lb += LT) {
        // weight tile: [l][k] rows, coalesced along k
#pragma unroll
        for (int t = 0; t < 8; ++t) {
            int row = (tid >> 6) + 4 * t;       // 0..31
            int kk = tid & 63;
            wt[row][kk] = weight[(size_t)(l0 + lb + row) * KK + kk];
        }
        // x tile (scaled by invn)
        int ll = tid & 31;
        int rb = tid >> 5;
        int gl = l0 + lb + ll;
        float iv = invn[gl];
#pragma unroll
        for (int p = 0; p < 16; ++p) {
            int c = rb + 8 * p;
            xt[ll][c] = x[(c0 + c) * LL + gl] * iv;
        }
        __syncthreads();
#pragma unroll 4
        for (int lt = 0; lt < LT; ++lt) {
            float wv[8], xv[4];
#pragma unroll
            for (int r = 0; r < 8; ++r) wv[r] = wt[lt][ty + 8 * r];
#pragma unroll
            for (int s = 0; s < 4; ++s) xv[s] = xt[lt][tx + 32 * s];
#pragma unroll
            for (int r = 0; r < 8; ++r)
#pragma unroll
                for (int s = 0; s < 4; ++s) acc[r][s] = fmaf(wv[r], xv[s], acc[r][s]);
        }
        __syncthreads();
    }
#pragma unroll
    for (int r = 0; r < 8; ++r)
#pragma unroll
        for (int s = 0; s < 4; ++s)
            atomicAdd(&accg[(ty + 8 * r) * CC + c0 + tx + 32 * s], acc[r][s]);
}

// ---------------------------------------------------------------- k4a: centroid subtract + row L2-norm
__global__ __launch_bounds__(256) void k4a_rownorm(const float* __restrict__ accg,
                                                   const float* __restrict__ S,
                                                   const float* __restrict__ cent,
                                                   float* __restrict__ out,
                                                   float* __restrict__ gsum) {
    __shared__ float red[256];
    int k = blockIdx.x;
    int tid = threadIdx.x;
    float Sk = S[k];
    float v0 = accg[k * CC + tid]       - Sk * cent[k * CC + tid];
    float v1 = accg[k * CC + tid + 256] - Sk * cent[k * CC + tid + 256];
    red[tid] = v0 * v0 + v1 * v1; __syncthreads();
    for (int off = 128; off > 0; off >>= 1) {
        if (tid < off) red[tid] += red[tid + off];
        __syncthreads();
    }
    float tot = red[0];
    float rn = 1.0f / fmaxf(sqrtf(tot), EPSF);
    out[k * CC + tid]       = v0 * rn;
    out[k * CC + tid + 256] = v1 * rn;
    if (tid == 0) atomicAdd(gsum, tot * rn * rn);
}

// ---------------------------------------------------------------- k4b: global L2 scale
__global__ __launch_bounds__(256) void k4b_gnorm(float* __restrict__ out,
                                                 const float* __restrict__ gsum) {
    float g = gsum[0];
    float rg = 1.0f / fmaxf(sqrtf(g), EPSF);
    int idx = blockIdx.x * 256 + threadIdx.x;
    out[idx] *= rg;
}

// ----------------------------------------------------------------
extern "C" void kernel_launch(void* const* d_in, const int* in_sizes, int n_in,
                              void* d_out, int out_size, void* d_ws, size_t ws_size,
                              hipStream_t stream) {
    const float* x      = (const float*)d_in[0];   // (512,192,192)
    const float* conv_w = (const float*)d_in[1];   // (64,512)
    const float* cent   = (const float*)d_in[2];   // (64,512)
    float* out = (float*)d_out;                    // 32768 fp32

    float* ws   = (float*)d_ws;
    float* wT   = ws;                               // 32768
    float* soft = ws + 32768;                       // KK*LL  (becomes weight in place)
    float* invn = soft + (size_t)KK * LL;           // LL
    ull*   keep = (ull*)(invn + LL);                // LL u64
    float* accg = (float*)(keep + LL);              // KK*CC
    float* S    = accg + (size_t)KK * CC;           // KK
    float* gsum = S + KK;                           // 1

    // zero accg + S + gsum (contiguous)
    hipMemsetAsync(accg, 0, ((size_t)KK * CC + KK + 1) * sizeof(float), stream);

    k0_transpose<<<(KK * CC) / 256, 256, 0, stream>>>(conv_w, wT);
    k1_logits<<<LL / 64, 256, 0, stream>>>(x, wT, soft, invn, keep);
    k2_weight<<<LL / 256, 256, 0, stream>>>(soft, keep);
    k2b_ssum<<<LL / 256, 256, 0, stream>>>(soft, S);
    k3_gemm<<<NCHUNK * (CC / CT), 256, 0, stream>>>(soft, x, invn, accg);
    k4a_rownorm<<<KK, 256, 0, stream>>>(accg, S, cent, out, gsum);
    k4b_gnorm<<<(KK * CC) / 256, 256, 0, stream>>>(out, gsum);
}